// Round 1
// baseline (96.776 us; speedup 1.0000x reference)
//
#include <hip/hip_runtime.h>
#include <hip/hip_bf16.h>
#include <stdint.h>

#define BATCH 256
#define INF   1024
#define OUTF  128
#define KD    8
#define OROW  1152   // INF + OUTF

#define TSLS 1032    // Tsl row stride in shorts: 1024 + 8 pad (keeps 16B align, spreads banks)
#define MLS  12      // Mloc row stride in floats: 8 + 4 pad (keeps 16B align, spreads banks)

typedef __attribute__((ext_vector_type(8))) short short8;
typedef __attribute__((ext_vector_type(4))) float f32x4;

__device__ __forceinline__ unsigned short f2bf(float f) {
    // RNE float->bf16 via the standard cast path (compiler emits HW cvt; m240:
    // scalar cast beats hand-written cvt_pk asm).
    __hip_bfloat16 h = __float2bfloat16(f);
    union { __hip_bfloat16 h; unsigned short u; } v; v.h = h;
    return v.u;
}

// Single fused kernel. Blocks 0..127: one output-feature o each.
//   Phase 1: stage T[:, o, :] -> LDS bf16 (layout Tsl[kd][k])
//   Phase 2: M[a][kd] = x @ T-slice via mfma_f32_16x16x32_bf16, M kept in LDS
//   Phase 3: c[a, o] = sum_b exp(-L1(M[a], M[b])) - 1, from LDS, no atomics
// Blocks 128..191: copy x -> out[:, 0:1024] (float4).
__global__ __launch_bounds__(512) void fused_kernel(
    const float* __restrict__ x, const float* __restrict__ T,
    float* __restrict__ out)
{
    const int bid = blockIdx.x;
    const int t = threadIdx.x;

    if (bid >= OUTF) {
        // ---- x copy: 64 blocks x 4 rows ----
        const int bx = bid - OUTF;                 // 0..63
        const float4* xs = (const float4*)x;
        #pragma unroll
        for (int p = 0; p < 2; ++p) {
            int g = bx * 1024 + p * 512 + t;       // global float4 index
            int row = g >> 8, col4 = g & 255;
            float4 v = xs[g];
            *(float4*)(out + (size_t)row * OROW + col4 * 4) = v;
        }
        return;
    }

    __shared__ __align__(16) unsigned short Tsl[8 * TSLS];   // 16.1 KB
    __shared__ __align__(16) float Mloc[256 * MLS];          // 12.3 KB
    __shared__ float red[256];                               // 1 KB

    const int o = bid;

    // ---- Phase 1: stage T[:, o, :] as bf16, transposed to Tsl[kd][k] ----
    for (int i = t; i < 8192; i += 512) {
        int kd = i & 7, k = i >> 3;
        Tsl[kd * TSLS + k] = f2bf(T[(size_t)k * (OUTF * KD) + o * KD + kd]);
    }
    __syncthreads();

    // ---- Phase 2: slice GEMM. Wave w owns M rows [w*32, w*32+32), full K ----
    const int wave = t >> 6, lane = t & 63;
    const int rc = lane & 15, quad = lane >> 4;
    const int abase = wave * 32;

    f32x4 acc0 = {0.f, 0.f, 0.f, 0.f}, acc1 = {0.f, 0.f, 0.f, 0.f};
    const float* pa0 = x + (size_t)(abase + rc) * INF + quad * 8;
    const float* pa1 = pa0 + 16 * INF;
    // B-frag: row n = rc (rc>=8 reads duplicate rows -> garbage cols 8..15, unused)
    const unsigned short* pb = Tsl + (rc & 7) * TSLS + quad * 8;

    #pragma unroll 4
    for (int ks = 0; ks < 32; ++ks) {
        const int k = ks * 32;
        float4 a0l = *(const float4*)(pa0 + k);
        float4 a0h = *(const float4*)(pa0 + k + 4);
        float4 a1l = *(const float4*)(pa1 + k);
        float4 a1h = *(const float4*)(pa1 + k + 4);
        short8 bf = *(const short8*)(pb + k);      // ds_read_b128
        short8 a0f, a1f;
        a0f[0] = (short)f2bf(a0l.x); a0f[1] = (short)f2bf(a0l.y);
        a0f[2] = (short)f2bf(a0l.z); a0f[3] = (short)f2bf(a0l.w);
        a0f[4] = (short)f2bf(a0h.x); a0f[5] = (short)f2bf(a0h.y);
        a0f[6] = (short)f2bf(a0h.z); a0f[7] = (short)f2bf(a0h.w);
        a1f[0] = (short)f2bf(a1l.x); a1f[1] = (short)f2bf(a1l.y);
        a1f[2] = (short)f2bf(a1l.z); a1f[3] = (short)f2bf(a1l.w);
        a1f[4] = (short)f2bf(a1h.x); a1f[5] = (short)f2bf(a1h.y);
        a1f[6] = (short)f2bf(a1h.z); a1f[7] = (short)f2bf(a1h.w);
        acc0 = __builtin_amdgcn_mfma_f32_16x16x32_bf16(a0f, bf, acc0, 0, 0, 0);
        acc1 = __builtin_amdgcn_mfma_f32_16x16x32_bf16(a1f, bf, acc1, 0, 0, 0);
    }

    // C/D layout: col = lane&15 (= kd), row = quad*4 + r   [measured m89/m91]
    if (rc < 8) {
        #pragma unroll
        for (int r = 0; r < 4; ++r) {
            Mloc[(abase + quad * 4 + r) * MLS + rc]      = acc0[r];
            Mloc[(abase + 16 + quad * 4 + r) * MLS + rc] = acc1[r];
        }
    }
    __syncthreads();

    // ---- Phase 3: pairwise L1 + exp, all from LDS ----
    const int a  = t & 255;
    const int bh = t >> 8;                         // wave-uniform b-half
    const float* ma = Mloc + a * MLS;
    float4 m0 = *(const float4*)(ma);
    float4 m1 = *(const float4*)(ma + 4);
    float ssum = 0.f;
    #pragma unroll 4
    for (int j = 0; j < 128; ++j) {
        const float* mb = Mloc + (bh * 128 + j) * MLS;   // uniform -> LDS broadcast
        float4 q0 = *(const float4*)(mb);
        float4 q1 = *(const float4*)(mb + 4);
        float d = fabsf(m0.x - q0.x) + fabsf(m0.y - q0.y)
                + fabsf(m0.z - q0.z) + fabsf(m0.w - q0.w)
                + fabsf(m1.x - q1.x) + fabsf(m1.y - q1.y)
                + fabsf(m1.z - q1.z) + fabsf(m1.w - q1.w);
        ssum += __expf(-d);
    }
    if (bh) red[a] = ssum;
    __syncthreads();
    if (!bh) out[(size_t)a * OROW + INF + o] = ssum + red[a] - 1.0f;
    // (self term exp(0)=1 cancelled by the -1)
}

extern "C" void kernel_launch(void* const* d_in, const int* in_sizes, int n_in,
                              void* d_out, int out_size, void* d_ws, size_t ws_size,
                              hipStream_t stream) {
    const float* x = (const float*)d_in[0];
    const float* T = (const float*)d_in[1];
    float* out = (float*)d_out;
    (void)d_ws; (void)ws_size;   // workspace no longer needed: M lives in LDS
    fused_kernel<<<OUTF + 64, 512, 0, stream>>>(x, T, out);
}

// Round 2
// 79.147 us; speedup vs baseline: 1.2227x; 1.2227x over previous
//
#include <hip/hip_runtime.h>
#include <stdint.h>

#define BATCH 256
#define INF   1024
#define OUTF  128
#define KD    8
#define NN    1024      // OUTF*KD
#define OROW  1152      // INF + OUTF

#define TSLS  1032      // Tsl row stride in shorts (16B-aligned, non-pow2 bank spread)
#define MLS   12        // Mloc row stride in floats (16B-aligned)
#define CHUNK_SH 16384  // shorts per x-chunk buffer: 256 rows x 64 cols bf16 = 32 KB

typedef __attribute__((ext_vector_type(8))) short short8;
typedef __attribute__((ext_vector_type(4))) float f32x4;

__device__ __forceinline__ unsigned short f2bf(float f) {
    union { float f; uint32_t u; } v; v.f = f;
    uint32_t r = v.u + 0x7FFFu + ((v.u >> 16) & 1u);   // RNE
    return (unsigned short)(r >> 16);
}

// K1: x -> out copy (fp32) + x -> xbf (bf16). 64 blocks x 256 threads.
__global__ __launch_bounds__(256) void prep_kernel(
    const float* __restrict__ x, float* __restrict__ out,
    unsigned short* __restrict__ xbf)
{
    int bx = blockIdx.x, t = threadIdx.x;
    #pragma unroll
    for (int p = 0; p < 4; ++p) {
        int a = bx * 4 + p;
        int j = t * 4;
        float4 v = *(const float4*)(x + (size_t)a * INF + j);
        *(float4*)(out + (size_t)a * OROW + j) = v;
        uint2 u;
        u.x = (uint32_t)f2bf(v.x) | ((uint32_t)f2bf(v.y) << 16);
        u.y = (uint32_t)f2bf(v.z) | ((uint32_t)f2bf(v.w) << 16);
        *(uint2*)(xbf + (size_t)a * INF + j) = u;
    }
}

// DMA one 256x64 bf16 chunk of xbf into LDS. Linear LDS dest (base+lane*16),
// row&7 XOR-swizzle applied on the per-lane GLOBAL source address (m173 pattern):
// LDS slot s of row r holds k-segment (s ^ (r&7)). One instr = 8 rows x 8 slots.
__device__ __forceinline__ void stage_chunk(
    const unsigned short* __restrict__ xbf, unsigned short* lbuf,
    int c, int wave, int lane)
{
    const int row_in = lane >> 3;        // 0..7 (== row&7 since rows are 8-aligned)
    const int s = lane & 7;              // 16B slot within the row
    const int koff = c * 64 + ((s ^ row_in) << 3);
    #pragma unroll
    for (int p = 0; p < 4; ++p) {
        const int i = wave * 4 + p;      // instr index 0..31, wave-uniform
        const unsigned short* src = xbf + (size_t)(i * 8 + row_in) * INF + koff;
        unsigned short* dst = lbuf + i * 512;   // 1024 B per instr, wave-uniform base
        __builtin_amdgcn_global_load_lds(
            (const __attribute__((address_space(1))) unsigned int*)src,
            (__attribute__((address_space(3))) unsigned int*)dst, 16, 0, 0);
    }
}

// K2: one block per output feature o. 512 threads = 8 waves.
//  GEMM: wave w owns M rows [w*32, w*32+32), full K, x from DMA-staged LDS chunks.
//  Pair: thread handles 4 a-rows x 32 b; LDS-only; direct (non-atomic) c write.
__global__ __launch_bounds__(512, 2) void fused_kernel(
    const float* __restrict__ T, const unsigned short* __restrict__ xbf,
    float* __restrict__ out)
{
    __shared__ __align__(16) unsigned short xls[3 * CHUNK_SH];   // 96 KB triple buffer
    __shared__ __align__(16) unsigned short Tsl[KD * TSLS];      // 16.1 KB
    __shared__ __align__(16) float Mloc[256 * MLS];              // 12 KB
    __shared__ float red[2048];                                  // 8 KB

    const int o = blockIdx.x;
    const int t = threadIdx.x;
    const int wave = t >> 6, lane = t & 63;

    // Kick off DMA of chunks 0 and 1 immediately (overlaps T staging).
    stage_chunk(xbf, xls, 0, wave, lane);
    stage_chunk(xbf, xls + CHUNK_SH, 1, wave, lane);

    // Stage T[:, o, :] -> Tsl[kd][k] bf16. float4 global reads (4 kd at once).
    #pragma unroll
    for (int it = 0; it < 4; ++it) {
        int i = it * 512 + t;            // 0..2047 float4 units
        int k = i >> 1, h = (i & 1) * 4;
        float4 v = *(const float4*)(T + (size_t)k * NN + o * KD + h);
        Tsl[(h + 0) * TSLS + k] = f2bf(v.x);
        Tsl[(h + 1) * TSLS + k] = f2bf(v.y);
        Tsl[(h + 2) * TSLS + k] = f2bf(v.z);
        Tsl[(h + 3) * TSLS + k] = f2bf(v.w);
    }
    __syncthreads();   // Tsl ready; full drain also lands chunks 0,1 (once, ok)

    const int rc = lane & 15, quad = lane >> 4, rc7 = rc & 7;
    const int abase = wave * 32;
    f32x4 acc0 = {0.f, 0.f, 0.f, 0.f}, acc1 = {0.f, 0.f, 0.f, 0.f};

    // Pipelined K-loop: entry outstanding (per wave) = {c, c+1} x4 DMA.
    // vmcnt(4) drains chunk c, leaves c+1 in flight; raw barrier (NO drain);
    // then issue chunk c+2 into the buffer chunk c-1 used (all waves are past
    // compute(c-1) by this barrier); then compute chunk c.
    for (int c = 0; c < 16; ++c) {
        if (c == 15) { asm volatile("s_waitcnt vmcnt(0)" ::: "memory"); }
        else         { asm volatile("s_waitcnt vmcnt(4)" ::: "memory"); }
        __builtin_amdgcn_sched_barrier(0);
        __builtin_amdgcn_s_barrier();
        if (c + 2 < 16)
            stage_chunk(xbf, xls + ((c + 2) % 3) * CHUNK_SH, c + 2, wave, lane);
        const unsigned short* cur = xls + (c % 3) * CHUNK_SH;
        #pragma unroll
        for (int kk = 0; kk < 2; ++kk) {
            const int sA = (((quad + (kk << 2)) ^ rc7) << 3);          // swizzled slot, shorts
            short8 A0 = *(const short8*)(cur + (abase + rc) * 64 + sA);
            short8 A1 = *(const short8*)(cur + (abase + 16 + rc) * 64 + sA);
            short8 Bf = *(const short8*)(Tsl + rc7 * TSLS + c * 64 + kk * 32 + quad * 8);
            acc0 = __builtin_amdgcn_mfma_f32_16x16x32_bf16(A0, Bf, acc0, 0, 0, 0);
            acc1 = __builtin_amdgcn_mfma_f32_16x16x32_bf16(A1, Bf, acc1, 0, 0, 0);
        }
    }

    // C/D layout: col = lane&15 (= kd, valid for rc<8), row = quad*4 + r  [m89/m91]
    if (rc < 8) {
        #pragma unroll
        for (int r = 0; r < 4; ++r) {
            Mloc[(abase + quad * 4 + r) * MLS + rc]      = acc0[r];
            Mloc[(abase + 16 + quad * 4 + r) * MLS + rc] = acc1[r];
        }
    }
    __syncthreads();

    // ---- Pair phase: 4 a-rows x 32 b per thread ----
    const int g = t & 63, ob = t >> 6;   // ob is wave-uniform -> broadcast q reads
    f32x4 m0[4], m1[4];
    #pragma unroll
    for (int ia = 0; ia < 4; ++ia) {
        const float* mp = Mloc + (ia * 64 + g) * MLS;
        m0[ia] = *(const f32x4*)(mp);
        m1[ia] = *(const f32x4*)(mp + 4);
    }
    float accs[4] = {0.f, 0.f, 0.f, 0.f};
    #pragma unroll 4
    for (int j = 0; j < 32; ++j) {
        const float* qp = Mloc + (ob * 32 + j) * MLS;
        f32x4 q0 = *(const f32x4*)(qp);
        f32x4 q1 = *(const f32x4*)(qp + 4);
        #pragma unroll
        for (int ia = 0; ia < 4; ++ia) {
            float d = fabsf(m0[ia][0] - q0[0]) + fabsf(m0[ia][1] - q0[1])
                    + fabsf(m0[ia][2] - q0[2]) + fabsf(m0[ia][3] - q0[3])
                    + fabsf(m1[ia][0] - q1[0]) + fabsf(m1[ia][1] - q1[1])
                    + fabsf(m1[ia][2] - q1[2]) + fabsf(m1[ia][3] - q1[3]);
            accs[ia] += __expf(-d);
        }
    }
    #pragma unroll
    for (int ia = 0; ia < 4; ++ia)
        red[(ob * 4 + ia) * 64 + g] = accs[ia];
    __syncthreads();
    if (t < 256) {
        int ia = t >> 6, gg = t & 63;
        float s = 0.f;
        #pragma unroll
        for (int ob2 = 0; ob2 < 8; ++ob2)
            s += red[(ob2 * 4 + ia) * 64 + gg];
        // self term exp(0)=1 cancelled by -1
        out[(size_t)(ia * 64 + gg) * OROW + INF + o] = s - 1.0f;
    }
}

extern "C" void kernel_launch(void* const* d_in, const int* in_sizes, int n_in,
                              void* d_out, int out_size, void* d_ws, size_t ws_size,
                              hipStream_t stream) {
    const float* x = (const float*)d_in[0];
    const float* T = (const float*)d_in[1];
    float* out = (float*)d_out;
    unsigned short* xbf = (unsigned short*)d_ws;   // 512 KB

    prep_kernel<<<64, 256, 0, stream>>>(x, out, xbf);
    fused_kernel<<<OUTF, 512, 0, stream>>>(T, xbf, out);
}